// Round 16
// baseline (129.059 us; speedup 1.0000x reference)
//
#include <hip/hip_runtime.h>
#include <hip/hip_bf16.h>

#define NB   8
#define CC   256
#define NN   4096            // H*W
#define NTOT (NB*NN)         // 32768
#define DQK  32
#define DV   128

typedef __attribute__((ext_vector_type(8))) short bf16x8;    // 8 bf16 in 4 VGPRs
typedef __attribute__((ext_vector_type(4))) short s16x4;
typedef __attribute__((ext_vector_type(4))) float f32x4;
typedef __attribute__((ext_vector_type(16))) float f32x16;
typedef __attribute__((ext_vector_type(4))) float float4v;
typedef __attribute__((ext_vector_type(4))) unsigned int u32x4;
typedef __attribute__((ext_vector_type(2))) unsigned int u32x2;

__device__ __forceinline__ short f2bf(float f) {
    __hip_bfloat16 h = __float2bfloat16(f);
    return *reinterpret_cast<short*>(&h);
}
__device__ __forceinline__ float bf2f(short s) {
    unsigned int u = ((unsigned int)(unsigned short)s) << 16;
    return __builtin_bit_cast(float, u);
}
__device__ __forceinline__ unsigned int cvtpk(float lo, float hi) {
    unsigned int r;
    asm("v_cvt_pk_bf16_f32 %0, %1, %2" : "=v"(r) : "v"(lo), "v"(hi));
    return r;
}
// v_permlane32_swap_b32 a, b: a' = [a(0:31), b(0:31)], b' = [a(32:63), b(32:63)]
__device__ __forceinline__ void plswap(unsigned int &a, unsigned int &b) {
    asm("v_permlane32_swap_b32 %0, %1" : "+v"(a), "+v"(b));
}

// -------- workspace layout (bytes) --------
#define OFF_F     0u                        // f  bf16 [NTOT][32]        2 MB
#define OFF_G     (2u<<20)                  // g  bf16 [NTOT][32]        2 MB (pre-scaled log2e)
#define OFF_VT    (4u<<20)                  // vtile bf16 (frag-tiled)   8 MB
#define OFF_OP    (12u<<20)                 // opart bf16 [NTOT][2][128] 16 MB
#define OFF_LS    (28u<<20)                 // lspart f32 [NTOT][2]      256 KB
#define OFF_WQKVT ((28u<<20)+(512u<<10))    // WqkvT bf16 [192][256]     96 KB
#define OFF_WOT   (OFF_WQKVT + 192u*256u*2u) // WoT bf16 [256][128]      64 KB

// ---------------- prep: transpose weights to bf16 ----------------
__global__ __launch_bounds__(256) void prep_kernel(
    const float* __restrict__ Wf, const float* __restrict__ Wg,
    const float* __restrict__ Wh, const float* __restrict__ Wo,
    short* __restrict__ WqkvT, short* __restrict__ WoT)
{
    int idx = blockIdx.x * 256 + threadIdx.x;
    if (idx < 192 * 256) {
        int j = idx >> 8, k = idx & 255;
        float v = (j < 32) ? Wf[k * 32 + j]
                : (j < 64) ? Wg[k * 32 + (j - 32)]
                           : Wh[k * 128 + (j - 64)];
        WqkvT[j * 256 + k] = f2bf(v);
    }
    int i2 = idx - 192 * 256;
    if (i2 >= 0 && i2 < 256 * 128) {
        int c = i2 >> 7, d = i2 & 127;
        WoT[c * 128 + d] = f2bf(Wo[d * 256 + c]);   // WoT[col][d]
    }
}

// ---------------- proj v2: [f|g|hv] = x @ [Wf|Wg|Wh] + bias ----------------
// 1024 blocks x 32 rows (4 blocks/CU, 16 waves/CU — occupancy lever that
// worked for out). Wave (rh, ch): rows rh*16..+16, col-half ch (6 tiles of
// 16 of the 192 cols). SWAPPED MFMA -> D[c][n], lane owns row n and 4
// consecutive channels. ALL fp32->bf16 via packed v_cvt_pk_bf16_f32.
// hv: LDS [d][n] transpose ([128][40] shorts, 16B-aligned rows) then 16B
// coalesced vtile stores. g pre-scaled by log2(e). XCD-swizzled.
__global__ __launch_bounds__(256) void proj_kernel(
    const float* __restrict__ x,
    const float* __restrict__ bf_, const float* __restrict__ bg_,
    const float* __restrict__ bh_,
    const short* __restrict__ WqkvT,
    short* __restrict__ fws, short* __restrict__ gws, short* __restrict__ vtile)
{
    __shared__ short hlds[128 * 40];   // [d][n] bf16, rows padded to 40

    int wid = threadIdx.x >> 6, lane = threadIdx.x & 63;
    int col16 = lane & 15, rq = lane >> 4;
    // XCD-aware bijective swizzle (1024 = 128 x 8): batch = bid&7 = XCD
    int bid = blockIdx.x;
    int sid = (bid & 7) * 128 + (bid >> 3);
    int b = sid >> 7, nt = sid & 127;
    int rh = wid & 1, ch = wid >> 1;
    int nloc = rh * 16 + col16;                   // local row 0..31
    int arow = sid * 32 + nloc;                   // global n
    int kt = nt >> 1, ksb = (nt & 1) * 2;         // vtile tile / kslot base

    f32x4 acc[6];
    #pragma unroll
    for (int i = 0; i < 6; ++i) acc[i] = (f32x4){0.f, 0.f, 0.f, 0.f};

    const float* xrow = x + (size_t)arow * CC;
    #pragma unroll
    for (int kk = 0; kk < 8; ++kk) {
        int k0 = kk * 32 + rq * 8;
        float4v u0 = *(const float4v*)(xrow + k0);
        float4v u1 = *(const float4v*)(xrow + k0 + 4);
        u32x4 avw = { cvtpk(u0[0], u0[1]), cvtpk(u0[2], u0[3]),
                      cvtpk(u1[0], u1[1]), cvtpk(u1[2], u1[3]) };
        bf16x8 av = __builtin_bit_cast(bf16x8, avw);
        #pragma unroll
        for (int nf = 0; nf < 6; ++nf) {
            int ct = ch * 6 + nf;
            bf16x8 bv = *(const bf16x8*)(WqkvT + (ct * 16 + col16) * 256 + k0);
            // swapped: W as A, x as B -> D[c][n]
            acc[nf] = __builtin_amdgcn_mfma_f32_16x16x32_bf16(bv, av, acc[nf], 0, 0, 0);
        }
    }

    if (ch == 0) {
        // f: tiles 0,1 (cols 0..31)
        #pragma unroll
        for (int nf = 0; nf < 2; ++nf) {
            int c0 = nf * 16 + rq * 4;
            float4v b4 = *(const float4v*)(bf_ + c0);
            u32x2 v = { cvtpk(acc[nf][0] + b4[0], acc[nf][1] + b4[1]),
                        cvtpk(acc[nf][2] + b4[2], acc[nf][3] + b4[3]) };
            *(u32x2*)(fws + (size_t)arow * DQK + c0) = v;
        }
        // g: tiles 2,3 (cols 32..63), pre-scaled by log2(e)
        #pragma unroll
        for (int nf = 2; nf < 4; ++nf) {
            int c0 = (nf - 2) * 16 + rq * 4;
            float4v b4 = *(const float4v*)(bg_ + c0);
            u32x2 v = { cvtpk((acc[nf][0] + b4[0]) * 1.44269504089f,
                              (acc[nf][1] + b4[1]) * 1.44269504089f),
                        cvtpk((acc[nf][2] + b4[2]) * 1.44269504089f,
                              (acc[nf][3] + b4[3]) * 1.44269504089f) };
            *(u32x2*)(gws + (size_t)arow * DQK + c0) = v;
        }
        // hv: tiles 4,5 -> d 0..31
        #pragma unroll
        for (int nf = 4; nf < 6; ++nf) {
            int d0 = (nf - 4) * 16 + rq * 4;
            float4v b4 = *(const float4v*)(bh_ + d0);
            unsigned int p01 = cvtpk(acc[nf][0] + b4[0], acc[nf][1] + b4[1]);
            unsigned int p23 = cvtpk(acc[nf][2] + b4[2], acc[nf][3] + b4[3]);
            hlds[(d0 + 0) * 40 + nloc] = (short)(p01 & 0xffff);
            hlds[(d0 + 1) * 40 + nloc] = (short)(p01 >> 16);
            hlds[(d0 + 2) * 40 + nloc] = (short)(p23 & 0xffff);
            hlds[(d0 + 3) * 40 + nloc] = (short)(p23 >> 16);
        }
    } else {
        // hv: tiles 6..11 -> d 32..127
        #pragma unroll
        for (int nf = 0; nf < 6; ++nf) {
            int d0 = (nf + 2) * 16 + rq * 4;
            float4v b4 = *(const float4v*)(bh_ + d0);
            unsigned int p01 = cvtpk(acc[nf][0] + b4[0], acc[nf][1] + b4[1]);
            unsigned int p23 = cvtpk(acc[nf][2] + b4[2], acc[nf][3] + b4[3]);
            hlds[(d0 + 0) * 40 + nloc] = (short)(p01 & 0xffff);
            hlds[(d0 + 1) * 40 + nloc] = (short)(p01 >> 16);
            hlds[(d0 + 2) * 40 + nloc] = (short)(p23 & 0xffff);
            hlds[(d0 + 3) * 40 + nloc] = (short)(p23 >> 16);
        }
    }
    __syncthreads();

    // vtile store: 512 vectors (128 d x 4 n-groups of 8), 2 per thread.
    // vtile element (b, n, d): kslot=(n_tile>>4), klh=(n_tile>>3)&1, j=n&7
    int t = threadIdx.x;
    #pragma unroll
    for (int i = 0; i < 2; ++i) {
        int v = i * 256 + t;
        int d = v >> 2, g = v & 3;
        bf16x8 vec = *(const bf16x8*)(&hlds[d * 40 + g * 8]);
        int ks = ksb + (g >> 1), klh = g & 1;
        size_t addr = (((size_t)(b * 64 + kt) * 4 + ks) * 2048)
                    + (d >> 5) * 512 + klh * 256 + (d & 31) * 8;
        *(bf16x8*)(vtile + addr) = vec;
    }
}

// ---------------- attn: barrier-free loop (EXACT R7 source form) ------------
// 1024 blocks (8 b x 2 ksh x 64 qtiles) x 256 thr; (256,4).
// Wave (qh, kh): QK^T quadrant (swapped: s[k][q], lane=q) -> exp2 -> pack ->
// PV transposed oT[d][q] = mfma(va, pb). NOTE: the PV section must stay in
// this nested-loop form — R11's inline-deref rewrite dropped VGPR 64->56 and
// the compiler serialized the va loads (109us vs 68us). Do not "clean up".
// R14 lesson: do NOT stagger the k-order (wave-desync regressed, +3.4us).
// VGPR must stay at 64 (=128 unified with acc) or occupancy drops (R9).
__global__ __launch_bounds__(256, 4) void attn_kernel(
    const short* __restrict__ fws, const short* __restrict__ gws,
    const short* __restrict__ vtile, short* __restrict__ opart,
    float* __restrict__ lspart)
{
    __shared__ __align__(16) char smem[33280];  // 32KB obuf + 512B lsbuf

    int t = threadIdx.x;
    int wid = t >> 6, lane = t & 63;
    int l31 = lane & 31, lh = lane >> 5;
    int qh = wid >> 1, kh = wid & 1;

    // XCD-aware swizzle: 1024 wgs % 8 == 0 -> bijective; batch per XCD
    int bid = blockIdx.x;
    int sid = (bid & 7) * 128 + (bid >> 3);
    int b = sid >> 7, rem = sid & 127;
    int ksh = rem >> 6, qt = rem & 63;
    int qbase = b * NN + qt * 64;
    int k0 = ksh * 32, kend = k0 + 32;   // 64-key tiles

    // g B-frags (col = q = qh*32+l31, k-elem = cs*16 + lh*8 + j)
    const short* grow = gws + (size_t)(qbase + qh * 32 + l31) * DQK;
    bf16x8 gb0 = *(const bf16x8*)(grow + lh * 8);
    bf16x8 gb1 = *(const bf16x8*)(grow + 16 + lh * 8);

    // f A-frags: row(key) = kb*64 + kh*32 + l31, elems = cs*16 + lh*8 + j
    int foff = (kh * 32 + l31) * DQK + lh * 8;
    const short* fS = fws + (size_t)b * NN * DQK;

    f32x16 oaccT[4], zero16;
    #pragma unroll
    for (int i = 0; i < 16; ++i) {
        zero16[i] = 0.f;
        oaccT[0][i] = 0.f; oaccT[1][i] = 0.f; oaccT[2][i] = 0.f; oaccT[3][i] = 0.f;
    }
    float lsum = 0.f;

    bf16x8 fc0 = *(const bf16x8*)(fS + (size_t)k0 * 2048 + foff);
    bf16x8 fc1 = *(const bf16x8*)(fS + (size_t)k0 * 2048 + foff + 16);

    for (int kb = k0; kb < kend; ++kb) {
        // prefetch next f frags (reads past kend land in ws, unused)
        const short* fnp = fS + (size_t)(kb + 1) * 2048 + foff;
        bf16x8 fn0 = *(const bf16x8*)(fnp);
        bf16x8 fn1 = *(const bf16x8*)(fnp + 16);

        // ---- QK^T quadrant: s[k_local][q], lane l31 = q ----
        f32x16 s = __builtin_amdgcn_mfma_f32_32x32x16_bf16(fc0, gb0, zero16, 0, 0, 0);
        s = __builtin_amdgcn_mfma_f32_32x32x16_bf16(fc1, gb1, s, 0, 0, 0);

        // ---- p = exp2(s'), per-lane (per-q) sum, pack ----
        unsigned int w[8];
        #pragma unroll
        for (int i = 0; i < 8; ++i) {
            float pa = __builtin_exp2f(s[2 * i]);
            float pb = __builtin_exp2f(s[2 * i + 1]);
            lsum += pa + pb;
            w[i] = cvtpk(pa, pb);
        }
        plswap(w[0], w[2]); plswap(w[1], w[3]);
        plswap(w[4], w[6]); plswap(w[5], w[7]);

        // ---- PV transposed: oT[d][q] += V^T . P^T, va direct from L2 ----
        const short* vb_kb = vtile + (((size_t)(b * 64 + kb) * 4 + kh * 2) * 2048)
                           + (size_t)lane * 8;
        #pragma unroll
        for (int ks = 0; ks < 2; ++ks) {
            u32x4 pw = { w[ks * 4], w[ks * 4 + 1], w[ks * 4 + 2], w[ks * 4 + 3] };
            bf16x8 pb_ = __builtin_bit_cast(bf16x8, pw);
            #pragma unroll
            for (int dt = 0; dt < 4; ++dt) {
                bf16x8 va = *(const bf16x8*)(vb_kb + ks * 2048 + dt * 512);
                oaccT[dt] = __builtin_amdgcn_mfma_f32_32x32x16_bf16(va, pb_, oaccT[dt], 0, 0, 0);
            }
        }
        fc0 = fn0; fc1 = fn1;
    }

    // ---- epilogue: kh merge + transpose via XOR-chunked LDS ----
    lsum += __shfl_xor(lsum, 32);               // combine lh halves (same q)
    float* lsbuf = (float*)(&smem[32768]);
    if (lh == 0) lsbuf[(qh * 2 + kh) * 32 + l31] = lsum;
    __syncthreads();                            // E1

    // obuf: [64 q][512B row = 32 f32x4 chunks, phys chunk = c ^ (q&31)]
    char* obuf = smem;
    if (kh == 1) {
        #pragma unroll
        for (int dt = 0; dt < 4; ++dt) {
            #pragma unroll
            for (int r = 0; r < 16; ++r) {
                int d = dt * 32 + (r & 3) + 8 * (r >> 2) + 4 * lh;
                int q = qh * 32 + l31;
                int byte = q * 512 + ((((d >> 2) ^ (q & 31)) << 4) | ((d & 3) << 2));
                *(float*)(obuf + byte) = oaccT[dt][r];
            }
        }
    }
    __syncthreads();                            // E2
    if (kh == 0) {
        float tot = lsbuf[qh * 64 + l31] + lsbuf[qh * 64 + 32 + l31];
        if (lh == 0) lspart[(size_t)(qbase + qh * 32 + l31) * 2 + ksh] = tot;
        float iv = 1.f / tot;
        #pragma unroll
        for (int dt = 0; dt < 4; ++dt) {
            #pragma unroll
            for (int r = 0; r < 16; ++r) {
                int d = dt * 32 + (r & 3) + 8 * (r >> 2) + 4 * lh;
                int q = qh * 32 + l31;
                int byte = q * 512 + ((((d >> 2) ^ (q & 31)) << 4) | ((d & 3) << 2));
                float* p = (float*)(obuf + byte);
                *p = (*p + oaccT[dt][r]) * iv;
            }
        }
    }
    __syncthreads();                            // E3
    // coop convert + coalesced store: t -> q = t>>2, dg = t&3 (32 d values)
    {
        int q = t >> 2, dg = t & 3;
        size_t orow = ((size_t)(qbase + q) * 2 + ksh) * 128 + dg * 32;
        #pragma unroll
        for (int cc = 0; cc < 8; cc += 2) {
            int c0 = dg * 8 + cc;
            f32x4 u0 = *(const f32x4*)(obuf + q * 512 + (((c0 ^ (q & 31)) << 4)));
            f32x4 u1 = *(const f32x4*)(obuf + q * 512 + ((((c0 + 1) ^ (q & 31)) << 4)));
            bf16x8 ov;
            ov[0]=f2bf(u0[0]); ov[1]=f2bf(u0[1]); ov[2]=f2bf(u0[2]); ov[3]=f2bf(u0[3]);
            ov[4]=f2bf(u1[0]); ov[5]=f2bf(u1[1]); ov[6]=f2bf(u1[2]); ov[7]=f2bf(u1[3]);
            *(bf16x8*)(opart + orow + cc * 4) = ov;
        }
    }
}

// ---------------- out: combine k-halves, then gamma*(o@Wo + bo) + x ----------
// SWAPPED MFMA: acc = mfma(WoT_frag, o_frag) -> D[c][n]; float4 epilogue.
// 1024 blocks x 32 rows -> 4 blocks/CU, 16 waves/CU; wave = (row-half,
// col-half). bfr merge uses packed cvtpk. XCD-swizzled (batch b on XCD b).
__global__ __launch_bounds__(256) void out_kernel(
    const short* __restrict__ opart, const float* __restrict__ lspart,
    const short* __restrict__ WoT,
    const float* __restrict__ bo, const float* __restrict__ gamma,
    const float* __restrict__ x, float* __restrict__ out)
{
    int wid = threadIdx.x >> 6, lane = threadIdx.x & 63;
    int col16 = lane & 15, rq = lane >> 4;
    // XCD-aware bijective swizzle (1024 = 128 x 8)
    int bid = blockIdx.x;
    int sid = (bid & 7) * 128 + (bid >> 3);
    int rh = wid & 1, ch = wid >> 1;             // row-half, col-half
    int arow = sid * 32 + rh * 16 + col16;

    float l0 = lspart[(size_t)arow * 2];
    float l1 = lspart[(size_t)arow * 2 + 1];
    float iv = 1.f / (l0 + l1);
    float w0 = l0 * iv, w1 = l1 * iv;

    const short* oprow = opart + (size_t)arow * 256;
    bf16x8 bfr[4];
    #pragma unroll
    for (int kk = 0; kk < 4; ++kk) {
        bf16x8 a0 = *(const bf16x8*)(oprow + kk * 32 + rq * 8);
        bf16x8 a1 = *(const bf16x8*)(oprow + 128 + kk * 32 + rq * 8);
        float m[8];
        #pragma unroll
        for (int j = 0; j < 8; ++j)
            m[j] = w0 * bf2f(a0[j]) + w1 * bf2f(a1[j]);
        u32x4 wv = { cvtpk(m[0], m[1]), cvtpk(m[2], m[3]),
                     cvtpk(m[4], m[5]), cvtpk(m[6], m[7]) };
        bfr[kk] = __builtin_bit_cast(bf16x8, wv);
    }

    f32x4 acc[8];
    #pragma unroll
    for (int i = 0; i < 8; ++i) acc[i] = (f32x4){0.f, 0.f, 0.f, 0.f};

    #pragma unroll
    for (int nf = 0; nf < 8; ++nf) {
        int nt = ch * 8 + nf;
        #pragma unroll
        for (int kk = 0; kk < 4; ++kk) {
            bf16x8 wfr = *(const bf16x8*)(WoT + (nt * 16 + col16) * DV + kk * 32 + rq * 8);
            // swapped: Wo as A, o as B -> D[c][n]
            acc[nf] = __builtin_amdgcn_mfma_f32_16x16x32_bf16(wfr, bfr[kk], acc[nf], 0, 0, 0);
        }
    }

    float gm = gamma[0];
    const float* xrow = x + (size_t)arow * CC;
    float* orow_ = out + (size_t)arow * CC;
    #pragma unroll
    for (int nf = 0; nf < 8; ++nf) {
        int c0 = (ch * 8 + nf) * 16 + rq * 4;
        float4v bo4 = *(const float4v*)(bo + c0);
        float4v xv = *(const float4v*)(xrow + c0);
        float4v ov;
        #pragma unroll
        for (int r = 0; r < 4; ++r)
            ov[r] = gm * (acc[nf][r] + bo4[r]) + xv[r];
        *(float4v*)(orow_ + c0) = ov;
    }
}

extern "C" void kernel_launch(void* const* d_in, const int* in_sizes, int n_in,
                              void* d_out, int out_size, void* d_ws, size_t ws_size,
                              hipStream_t stream)
{
    const float* x     = (const float*)d_in[0];
    const float* Wf    = (const float*)d_in[1];
    const float* bf_   = (const float*)d_in[2];
    const float* Wg    = (const float*)d_in[3];
    const float* bg_   = (const float*)d_in[4];
    const float* Wh    = (const float*)d_in[5];
    const float* bh_   = (const float*)d_in[6];
    const float* Wo    = (const float*)d_in[7];
    const float* bo    = (const float*)d_in[8];
    const float* gamma = (const float*)d_in[9];

    char* ws = (char*)d_ws;
    short* fws   = (short*)(ws + OFF_F);
    short* gws   = (short*)(ws + OFF_G);
    short* vtile = (short*)(ws + OFF_VT);
    short* opart = (short*)(ws + OFF_OP);
    float* lsp   = (float*)(ws + OFF_LS);
    short* WqkvT = (short*)(ws + OFF_WQKVT);
    short* WoT   = (short*)(ws + OFF_WOT);
    float* out   = (float*)d_out;

    hipLaunchKernelGGL(prep_kernel, dim3(320), dim3(256), 0, stream, Wf, Wg, Wh, Wo, WqkvT, WoT);
    hipLaunchKernelGGL(proj_kernel, dim3(1024), dim3(256), 0, stream,
                       x, bf_, bg_, bh_, WqkvT, fws, gws, vtile);
    hipLaunchKernelGGL(attn_kernel, dim3(1024), dim3(256), 0, stream, fws, gws, vtile, opart, lsp);
    hipLaunchKernelGGL(out_kernel, dim3(1024), dim3(256), 0, stream, opart, lsp, WoT, bo, gamma, x, out);
}

// Round 17
// 125.970 us; speedup vs baseline: 1.0245x; 1.0245x over previous
//
#include <hip/hip_runtime.h>
#include <hip/hip_bf16.h>

#define NB   8
#define CC   256
#define NN   4096            // H*W
#define NTOT (NB*NN)         // 32768
#define DQK  32
#define DV   128

typedef __attribute__((ext_vector_type(8))) short bf16x8;    // 8 bf16 in 4 VGPRs
typedef __attribute__((ext_vector_type(4))) short s16x4;
typedef __attribute__((ext_vector_type(4))) float f32x4;
typedef __attribute__((ext_vector_type(16))) float f32x16;
typedef __attribute__((ext_vector_type(4))) float float4v;
typedef __attribute__((ext_vector_type(4))) unsigned int u32x4;

__device__ __forceinline__ short f2bf(float f) {
    __hip_bfloat16 h = __float2bfloat16(f);
    return *reinterpret_cast<short*>(&h);
}
__device__ __forceinline__ float bf2f(short s) {
    unsigned int u = ((unsigned int)(unsigned short)s) << 16;
    return __builtin_bit_cast(float, u);
}
__device__ __forceinline__ unsigned int cvtpk(float lo, float hi) {
    unsigned int r;
    asm("v_cvt_pk_bf16_f32 %0, %1, %2" : "=v"(r) : "v"(lo), "v"(hi));
    return r;
}
// v_permlane32_swap_b32 a, b: a' = [a(0:31), b(0:31)], b' = [a(32:63), b(32:63)]
__device__ __forceinline__ void plswap(unsigned int &a, unsigned int &b) {
    asm("v_permlane32_swap_b32 %0, %1" : "+v"(a), "+v"(b));
}

// -------- workspace layout (bytes) --------
#define OFF_F     0u                        // f  bf16 [NTOT][32]        2 MB
#define OFF_G     (2u<<20)                  // g  bf16 [NTOT][32]        2 MB (pre-scaled log2e)
#define OFF_VT    (4u<<20)                  // vtile bf16 (frag-tiled)   8 MB
#define OFF_OP    (12u<<20)                 // opart bf16 [NTOT][2][128] 16 MB
#define OFF_LS    (28u<<20)                 // lspart f32 [NTOT][2]      256 KB
#define OFF_WQKVT ((28u<<20)+(512u<<10))    // WqkvT bf16 [192][256]     96 KB
#define OFF_WOT   (OFF_WQKVT + 192u*256u*2u) // WoT bf16 [256][128]      64 KB

// ---------------- prep: transpose weights to bf16 ----------------
__global__ __launch_bounds__(256) void prep_kernel(
    const float* __restrict__ Wf, const float* __restrict__ Wg,
    const float* __restrict__ Wh, const float* __restrict__ Wo,
    short* __restrict__ WqkvT, short* __restrict__ WoT)
{
    int idx = blockIdx.x * 256 + threadIdx.x;
    if (idx < 192 * 256) {
        int j = idx >> 8, k = idx & 255;
        float v = (j < 32) ? Wf[k * 32 + j]
                : (j < 64) ? Wg[k * 32 + (j - 32)]
                           : Wh[k * 128 + (j - 64)];
        WqkvT[j * 256 + k] = f2bf(v);
    }
    int i2 = idx - 192 * 256;
    if (i2 >= 0 && i2 < 256 * 128) {
        int c = i2 >> 7, d = i2 & 127;
        WoT[c * 128 + d] = f2bf(Wo[d * 256 + c]);   // WoT[col][d]
    }
}

// ---------------- proj: [f|g|hv] = x @ [Wf|Wg|Wh] + bias ----------------
// R15 form: 512 blocks x 64 rows (each x row read ONCE — R16's 1024x32
// split duplicated x reads across col-half waves and regressed +3us).
// SWAPPED MFMA: acc = mfma(W_frag, x_frag) -> D[c][n], lane owns row n and
// 4 CONSECUTIVE channels per tile. f/g: 8B stores. hv: LDS [d][n] transpose
// then 16B coalesced vtile stores. g pre-scaled by log2(e). XCD-swizzled.
__global__ __launch_bounds__(256) void proj_kernel(
    const float* __restrict__ x,
    const float* __restrict__ bf_, const float* __restrict__ bg_,
    const float* __restrict__ bh_,
    const short* __restrict__ WqkvT,
    short* __restrict__ fws, short* __restrict__ gws, short* __restrict__ vtile)
{
    __shared__ short hlds[128 * 72];   // [d][n] bf16, rows padded to 72

    int wid = threadIdx.x >> 6, lane = threadIdx.x & 63;
    int col16 = lane & 15, rq = lane >> 4;
    // XCD-aware bijective swizzle (512 = 64 x 8): batch = sid>>6 = bid&7 = XCD
    int bid = blockIdx.x;
    int sid = (bid & 7) * 64 + (bid >> 3);
    int nloc = wid * 16 + col16;                  // local row 0..63
    int arow = sid * 64 + nloc;                   // global n
    int b = sid >> 6, kt = sid & 63;

    f32x4 acc[12];
    #pragma unroll
    for (int i = 0; i < 12; ++i) acc[i] = (f32x4){0.f, 0.f, 0.f, 0.f};

    const float* xrow = x + (size_t)arow * CC;
    #pragma unroll
    for (int kk = 0; kk < 8; ++kk) {
        int k0 = kk * 32 + rq * 8;
        float4v u0 = *(const float4v*)(xrow + k0);
        float4v u1 = *(const float4v*)(xrow + k0 + 4);
        bf16x8 av;
        av[0]=f2bf(u0[0]); av[1]=f2bf(u0[1]); av[2]=f2bf(u0[2]); av[3]=f2bf(u0[3]);
        av[4]=f2bf(u1[0]); av[5]=f2bf(u1[1]); av[6]=f2bf(u1[2]); av[7]=f2bf(u1[3]);
        #pragma unroll
        for (int nf = 0; nf < 12; ++nf) {
            bf16x8 bv = *(const bf16x8*)(WqkvT + (nf * 16 + col16) * 256 + k0);
            // swapped: W as A, x as B -> D[c][n]
            acc[nf] = __builtin_amdgcn_mfma_f32_16x16x32_bf16(bv, av, acc[nf], 0, 0, 0);
        }
    }

    // ---- f / g: vectorized 8B stores (4 consecutive c per tile) ----
    #pragma unroll
    for (int nf = 0; nf < 2; ++nf) {
        int c0 = nf * 16 + rq * 4;
        float4v b4 = *(const float4v*)(bf_ + c0);
        s16x4 v = { f2bf(acc[nf][0] + b4[0]), f2bf(acc[nf][1] + b4[1]),
                    f2bf(acc[nf][2] + b4[2]), f2bf(acc[nf][3] + b4[3]) };
        *(s16x4*)(fws + (size_t)arow * DQK + c0) = v;
    }
    #pragma unroll
    for (int nf = 2; nf < 4; ++nf) {
        int c0 = (nf - 2) * 16 + rq * 4;
        float4v b4 = *(const float4v*)(bg_ + c0);
        s16x4 v = { f2bf((acc[nf][0] + b4[0]) * 1.44269504089f),
                    f2bf((acc[nf][1] + b4[1]) * 1.44269504089f),
                    f2bf((acc[nf][2] + b4[2]) * 1.44269504089f),
                    f2bf((acc[nf][3] + b4[3]) * 1.44269504089f) };
        *(s16x4*)(gws + (size_t)arow * DQK + c0) = v;
    }

    // ---- hv: dump to LDS [d][nloc], then coalesced vtile stores ----
    #pragma unroll
    for (int nf = 4; nf < 12; ++nf) {
        int d0 = (nf - 4) * 16 + rq * 4;
        float4v b4 = *(const float4v*)(bh_ + d0);
        #pragma unroll
        for (int r = 0; r < 4; ++r)
            hlds[(d0 + r) * 72 + nloc] = f2bf(acc[nf][r] + b4[r]);
    }
    __syncthreads();

    int t = threadIdx.x;
    int l31 = t & 31, dt = (t >> 5) & 3, klh = t >> 7;   // t<256 -> klh 0..1
    int d = dt * 32 + l31;
    #pragma unroll
    for (int kslot = 0; kslot < 4; ++kslot) {
        bf16x8 v = *(const bf16x8*)(&hlds[d * 72 + kslot * 16 + klh * 8]);
        size_t addr = (((size_t)(b * 64 + kt) * 4 + kslot) * 2048)
                    + dt * 512 + klh * 256 + l31 * 8;
        *(bf16x8*)(vtile + addr) = v;
    }
}

// ---------------- attn: barrier-free loop (EXACT R7 source form) ------------
// 1024 blocks (8 b x 2 ksh x 64 qtiles) x 256 thr; (256,4).
// Wave (qh, kh): QK^T quadrant (swapped: s[k][q], lane=q) -> exp2 -> pack ->
// PV transposed oT[d][q] = mfma(va, pb). NOTE: the PV section must stay in
// this nested-loop form — R11's inline-deref rewrite dropped VGPR 64->56 and
// the compiler serialized the va loads (109us vs 68us). Do not "clean up".
// R14 lesson: do NOT stagger the k-order (wave-desync regressed, +3.4us).
// VGPR must stay at 64 (=128 unified with acc) or occupancy drops (R9).
__global__ __launch_bounds__(256, 4) void attn_kernel(
    const short* __restrict__ fws, const short* __restrict__ gws,
    const short* __restrict__ vtile, short* __restrict__ opart,
    float* __restrict__ lspart)
{
    __shared__ __align__(16) char smem[33280];  // 32KB obuf + 512B lsbuf

    int t = threadIdx.x;
    int wid = t >> 6, lane = t & 63;
    int l31 = lane & 31, lh = lane >> 5;
    int qh = wid >> 1, kh = wid & 1;

    // XCD-aware swizzle: 1024 wgs % 8 == 0 -> bijective; batch per XCD
    int bid = blockIdx.x;
    int sid = (bid & 7) * 128 + (bid >> 3);
    int b = sid >> 7, rem = sid & 127;
    int ksh = rem >> 6, qt = rem & 63;
    int qbase = b * NN + qt * 64;
    int k0 = ksh * 32, kend = k0 + 32;   // 64-key tiles

    // g B-frags (col = q = qh*32+l31, k-elem = cs*16 + lh*8 + j)
    const short* grow = gws + (size_t)(qbase + qh * 32 + l31) * DQK;
    bf16x8 gb0 = *(const bf16x8*)(grow + lh * 8);
    bf16x8 gb1 = *(const bf16x8*)(grow + 16 + lh * 8);

    // f A-frags: row(key) = kb*64 + kh*32 + l31, elems = cs*16 + lh*8 + j
    int foff = (kh * 32 + l31) * DQK + lh * 8;
    const short* fS = fws + (size_t)b * NN * DQK;

    f32x16 oaccT[4], zero16;
    #pragma unroll
    for (int i = 0; i < 16; ++i) {
        zero16[i] = 0.f;
        oaccT[0][i] = 0.f; oaccT[1][i] = 0.f; oaccT[2][i] = 0.f; oaccT[3][i] = 0.f;
    }
    float lsum = 0.f;

    bf16x8 fc0 = *(const bf16x8*)(fS + (size_t)k0 * 2048 + foff);
    bf16x8 fc1 = *(const bf16x8*)(fS + (size_t)k0 * 2048 + foff + 16);

    for (int kb = k0; kb < kend; ++kb) {
        // prefetch next f frags (reads past kend land in ws, unused)
        const short* fnp = fS + (size_t)(kb + 1) * 2048 + foff;
        bf16x8 fn0 = *(const bf16x8*)(fnp);
        bf16x8 fn1 = *(const bf16x8*)(fnp + 16);

        // ---- QK^T quadrant: s[k_local][q], lane l31 = q ----
        f32x16 s = __builtin_amdgcn_mfma_f32_32x32x16_bf16(fc0, gb0, zero16, 0, 0, 0);
        s = __builtin_amdgcn_mfma_f32_32x32x16_bf16(fc1, gb1, s, 0, 0, 0);

        // ---- p = exp2(s'), per-lane (per-q) sum, pack ----
        unsigned int w[8];
        #pragma unroll
        for (int i = 0; i < 8; ++i) {
            float pa = __builtin_exp2f(s[2 * i]);
            float pb = __builtin_exp2f(s[2 * i + 1]);
            lsum += pa + pb;
            w[i] = cvtpk(pa, pb);
        }
        plswap(w[0], w[2]); plswap(w[1], w[3]);
        plswap(w[4], w[6]); plswap(w[5], w[7]);

        // ---- PV transposed: oT[d][q] += V^T . P^T, va direct from L2 ----
        const short* vb_kb = vtile + (((size_t)(b * 64 + kb) * 4 + kh * 2) * 2048)
                           + (size_t)lane * 8;
        #pragma unroll
        for (int ks = 0; ks < 2; ++ks) {
            u32x4 pw = { w[ks * 4], w[ks * 4 + 1], w[ks * 4 + 2], w[ks * 4 + 3] };
            bf16x8 pb_ = __builtin_bit_cast(bf16x8, pw);
            #pragma unroll
            for (int dt = 0; dt < 4; ++dt) {
                bf16x8 va = *(const bf16x8*)(vb_kb + ks * 2048 + dt * 512);
                oaccT[dt] = __builtin_amdgcn_mfma_f32_32x32x16_bf16(va, pb_, oaccT[dt], 0, 0, 0);
            }
        }
        fc0 = fn0; fc1 = fn1;
    }

    // ---- epilogue: kh merge + transpose via XOR-chunked LDS ----
    lsum += __shfl_xor(lsum, 32);               // combine lh halves (same q)
    float* lsbuf = (float*)(&smem[32768]);
    if (lh == 0) lsbuf[(qh * 2 + kh) * 32 + l31] = lsum;
    __syncthreads();                            // E1

    // obuf: [64 q][512B row = 32 f32x4 chunks, phys chunk = c ^ (q&31)]
    char* obuf = smem;
    if (kh == 1) {
        #pragma unroll
        for (int dt = 0; dt < 4; ++dt) {
            #pragma unroll
            for (int r = 0; r < 16; ++r) {
                int d = dt * 32 + (r & 3) + 8 * (r >> 2) + 4 * lh;
                int q = qh * 32 + l31;
                int byte = q * 512 + ((((d >> 2) ^ (q & 31)) << 4) | ((d & 3) << 2));
                *(float*)(obuf + byte) = oaccT[dt][r];
            }
        }
    }
    __syncthreads();                            // E2
    if (kh == 0) {
        float tot = lsbuf[qh * 64 + l31] + lsbuf[qh * 64 + 32 + l31];
        if (lh == 0) lspart[(size_t)(qbase + qh * 32 + l31) * 2 + ksh] = tot;
        float iv = 1.f / tot;
        #pragma unroll
        for (int dt = 0; dt < 4; ++dt) {
            #pragma unroll
            for (int r = 0; r < 16; ++r) {
                int d = dt * 32 + (r & 3) + 8 * (r >> 2) + 4 * lh;
                int q = qh * 32 + l31;
                int byte = q * 512 + ((((d >> 2) ^ (q & 31)) << 4) | ((d & 3) << 2));
                float* p = (float*)(obuf + byte);
                *p = (*p + oaccT[dt][r]) * iv;
            }
        }
    }
    __syncthreads();                            // E3
    // coop convert + coalesced store: t -> q = t>>2, dg = t&3 (32 d values)
    {
        int q = t >> 2, dg = t & 3;
        size_t orow = ((size_t)(qbase + q) * 2 + ksh) * 128 + dg * 32;
        #pragma unroll
        for (int cc = 0; cc < 8; cc += 2) {
            int c0 = dg * 8 + cc;
            f32x4 u0 = *(const f32x4*)(obuf + q * 512 + (((c0 ^ (q & 31)) << 4)));
            f32x4 u1 = *(const f32x4*)(obuf + q * 512 + ((((c0 + 1) ^ (q & 31)) << 4)));
            bf16x8 ov;
            ov[0]=f2bf(u0[0]); ov[1]=f2bf(u0[1]); ov[2]=f2bf(u0[2]); ov[3]=f2bf(u0[3]);
            ov[4]=f2bf(u1[0]); ov[5]=f2bf(u1[1]); ov[6]=f2bf(u1[2]); ov[7]=f2bf(u1[3]);
            *(bf16x8*)(opart + orow + cc * 4) = ov;
        }
    }
}

// ---------------- out: combine k-halves, then gamma*(o@Wo + bo) + x ----------
// SWAPPED MFMA: acc = mfma(WoT_frag, o_frag) -> D[c][n]; float4 epilogue.
// 1024 blocks x 32 rows -> 4 blocks/CU, 16 waves/CU; wave = (row-half,
// col-half), acc 8 tiles (32 VGPR). XCD-swizzled (batch b on XCD b).
__global__ __launch_bounds__(256) void out_kernel(
    const short* __restrict__ opart, const float* __restrict__ lspart,
    const short* __restrict__ WoT,
    const float* __restrict__ bo, const float* __restrict__ gamma,
    const float* __restrict__ x, float* __restrict__ out)
{
    int wid = threadIdx.x >> 6, lane = threadIdx.x & 63;
    int col16 = lane & 15, rq = lane >> 4;
    // XCD-aware bijective swizzle (1024 = 128 x 8)
    int bid = blockIdx.x;
    int sid = (bid & 7) * 128 + (bid >> 3);
    int rh = wid & 1, ch = wid >> 1;             // row-half, col-half
    int arow = sid * 32 + rh * 16 + col16;

    float l0 = lspart[(size_t)arow * 2];
    float l1 = lspart[(size_t)arow * 2 + 1];
    float iv = 1.f / (l0 + l1);
    float w0 = l0 * iv, w1 = l1 * iv;

    const short* oprow = opart + (size_t)arow * 256;
    bf16x8 bfr[4];
    #pragma unroll
    for (int kk = 0; kk < 4; ++kk) {
        bf16x8 a0 = *(const bf16x8*)(oprow + kk * 32 + rq * 8);
        bf16x8 a1 = *(const bf16x8*)(oprow + 128 + kk * 32 + rq * 8);
        bf16x8 af;
        #pragma unroll
        for (int j = 0; j < 8; ++j)
            af[j] = f2bf(w0 * bf2f(a0[j]) + w1 * bf2f(a1[j]));
        bfr[kk] = af;
    }

    f32x4 acc[8];
    #pragma unroll
    for (int i = 0; i < 8; ++i) acc[i] = (f32x4){0.f, 0.f, 0.f, 0.f};

    #pragma unroll
    for (int nf = 0; nf < 8; ++nf) {
        int nt = ch * 8 + nf;
        #pragma unroll
        for (int kk = 0; kk < 4; ++kk) {
            bf16x8 wfr = *(const bf16x8*)(WoT + (nt * 16 + col16) * DV + kk * 32 + rq * 8);
            // swapped: Wo as A, o as B -> D[c][n]
            acc[nf] = __builtin_amdgcn_mfma_f32_16x16x32_bf16(wfr, bfr[kk], acc[nf], 0, 0, 0);
        }
    }

    float gm = gamma[0];
    const float* xrow = x + (size_t)arow * CC;
    float* orow_ = out + (size_t)arow * CC;
    #pragma unroll
    for (int nf = 0; nf < 8; ++nf) {
        int c0 = (ch * 8 + nf) * 16 + rq * 4;
        float4v bo4 = *(const float4v*)(bo + c0);
        float4v xv = *(const float4v*)(xrow + c0);
        float4v ov;
        #pragma unroll
        for (int r = 0; r < 4; ++r)
            ov[r] = gm * (acc[nf][r] + bo4[r]) + xv[r];
        *(float4v*)(orow_ + c0) = ov;
    }
}

extern "C" void kernel_launch(void* const* d_in, const int* in_sizes, int n_in,
                              void* d_out, int out_size, void* d_ws, size_t ws_size,
                              hipStream_t stream)
{
    const float* x     = (const float*)d_in[0];
    const float* Wf    = (const float*)d_in[1];
    const float* bf_   = (const float*)d_in[2];
    const float* Wg    = (const float*)d_in[3];
    const float* bg_   = (const float*)d_in[4];
    const float* Wh    = (const float*)d_in[5];
    const float* bh_   = (const float*)d_in[6];
    const float* Wo    = (const float*)d_in[7];
    const float* bo    = (const float*)d_in[8];
    const float* gamma = (const float*)d_in[9];

    char* ws = (char*)d_ws;
    short* fws   = (short*)(ws + OFF_F);
    short* gws   = (short*)(ws + OFF_G);
    short* vtile = (short*)(ws + OFF_VT);
    short* opart = (short*)(ws + OFF_OP);
    float* lsp   = (float*)(ws + OFF_LS);
    short* WqkvT = (short*)(ws + OFF_WQKVT);
    short* WoT   = (short*)(ws + OFF_WOT);
    float* out   = (float*)d_out;

    hipLaunchKernelGGL(prep_kernel, dim3(320), dim3(256), 0, stream, Wf, Wg, Wh, Wo, WqkvT, WoT);
    hipLaunchKernelGGL(proj_kernel, dim3(512), dim3(256), 0, stream,
                       x, bf_, bg_, bh_, WqkvT, fws, gws, vtile);
    hipLaunchKernelGGL(attn_kernel, dim3(1024), dim3(256), 0, stream, fws, gws, vtile, opart, lsp);
    hipLaunchKernelGGL(out_kernel, dim3(1024), dim3(256), 0, stream, opart, lsp, WoT, bo, gamma, x, out);
}